// Round 1
// baseline (969.131 us; speedup 1.0000x reference)
//
#include <hip/hip_runtime.h>
#include <hip/hip_bf16.h>

// dims (fixed by the reference): Bk=16, n=256, E=768, G=128, Cout_g=256, Cin_g=192
// B=4, K=4, L=16, H=16, D=64.  out = [pooled 16*768][batch 131072*Tmax][valid 4*Tmax]

typedef float f32x4 __attribute__((ext_vector_type(4)));
typedef __bf16 bf16x8 __attribute__((ext_vector_type(8)));
typedef unsigned short u16x4 __attribute__((ext_vector_type(4)));
typedef unsigned short u16x8 __attribute__((ext_vector_type(8)));

__device__ __forceinline__ unsigned short f2bf(float f) {
    union { float f; unsigned u; } v; v.f = f;
    unsigned r = v.u + 0x7FFFu + ((v.u >> 16) & 1u);   // round-to-nearest-even
    return (unsigned short)(r >> 16);
}

__device__ __forceinline__ bf16x8 ldfrag(const unsigned short* p) {
    u16x8 r = *(const u16x8*)p;
    return __builtin_bit_cast(bf16x8, r);
}

// ws layout (int32): [0..15] len per bseq, [16..31] cum per bseq, [32..35] total per b

__global__ void prep_kernel(const float* __restrict__ lh, const int* __restrict__ mask,
                            float* __restrict__ pooled, int* __restrict__ ws) {
    int bs = blockIdx.x;      // 0..15
    int tid = threadIdx.x;    // 0..255
    __shared__ int s_len;
    if (tid == 0) s_len = 0;
    __syncthreads();
    int m = mask[bs * 256 + tid];
#pragma unroll
    for (int off = 32; off > 0; off >>= 1) m += __shfl_down(m, off);
    if ((tid & 63) == 0) atomicAdd(&s_len, m);
    __syncthreads();
    int len = s_len;
    if (tid == 0) ws[bs] = len;
    float inv = 1.0f / (float)len;
    for (int e = tid; e < 768; e += 256) {
        float s = 0.f;
        for (int t = 0; t < len; ++t) s += lh[(size_t)(bs * 256 + t) * 768 + e];
        pooled[bs * 768 + e] = s * inv;
    }
}

__global__ void cums_kernel(int* __restrict__ ws, float* __restrict__ valid_out, int Tmax) {
    if (threadIdx.x == 0) {
        for (int b = 0; b < 4; ++b) {
            int c = 0;
            for (int j = 0; j < 4; ++j) { ws[16 + b * 4 + j] = c; c += ws[b * 4 + j]; }
            ws[32 + b] = c;
        }
    }
    __syncthreads();
    for (int i = threadIdx.x; i < 4 * Tmax; i += blockDim.x) {
        int b = i / Tmax;
        int T = i - b * Tmax;
        valid_out[i] = (T < ws[32 + b]) ? 1.0f : 0.0f;   // whole out buffer is fp32
    }
}

// zero batch[l,s,b,h,T,d] for T in [total[b], Tmax)
__global__ void zerotail_kernel(float* __restrict__ batch, const int* __restrict__ ws,
                                int Tmax, int tailN) {
    int i = blockIdx.x * 256 + threadIdx.x;
    int per = tailN * 8192;                 // 8192 float4 per (b,T)
    if (i >= 4 * per) return;
    int b = i / per;
    int r = i - b * per;
    int toff = r >> 13;
    int q = r & 8191;                       // l*512 + s*256 + h*16 + dq
    int T = Tmax - 1 - toff;
    if (T < ws[32 + b]) return;
    int l = q >> 9, s = (q >> 8) & 1, h = (q >> 4) & 15, dq = q & 15;
    size_t off = ((((size_t)((l * 2 + s) * 4 + b) * 16 + h) * Tmax + T) * 64) + (dq << 2);
    f32x4 z = {0.f, 0.f, 0.f, 0.f};
    *(f32x4*)(batch + off) = z;
}

// One block per (bseq, g, mt, nt): 128x128 tile of the 256x256 (o x t) group GEMM, K=192
__global__ __launch_bounds__(256) void gemm_kernel(
    const float* __restrict__ lh, const float* __restrict__ wgt,
    const float* __restrict__ bias, const int* __restrict__ ws,
    float* __restrict__ out, int Tmax) {
    __shared__ __align__(16) unsigned short As[128][72];   // [o][k], pad 8
    __shared__ __align__(16) unsigned short Bs[128][72];   // [t][k], pad 8

    int x = blockIdx.x;
    int g  = x & 127;
    int mt = (x >> 7) & 1;
    int nt = (x >> 8) & 1;
    int bs = x >> 9;

    int len = ws[bs];
    int tbase = nt * 128;
    if (tbase >= len) return;               // uniform per block

    int beta = g & 3;
    const float* Ag = wgt + (size_t)g * 49152 + (size_t)mt * 128 * 192;
    const float* Bg = lh + (size_t)bs * 196608 + (size_t)tbase * 768 + beta * 192;

    int tid = threadIdx.x;
    int lane = tid & 63;
    int wave = tid >> 6;
    int wm = wave >> 1, wn = wave & 1;

    f32x4 acc[4][4] = {};

    for (int kk = 0; kk < 192; kk += 64) {
        // stage 128 rows x 64 floats for A and B, fp32 -> bf16
#pragma unroll
        for (int it = 0; it < 8; ++it) {
            int idx = tid + (it << 8);      // 0..2047
            int row = idx >> 4;
            int c4  = (idx & 15) << 2;      // float offset within the 64
            f32x4 av = *(const f32x4*)(Ag + row * 192 + kk + c4);
            f32x4 bv = *(const f32x4*)(Bg + row * 768 + kk + c4);
            u16x4 aw = { f2bf(av[0]), f2bf(av[1]), f2bf(av[2]), f2bf(av[3]) };
            u16x4 bw = { f2bf(bv[0]), f2bf(bv[1]), f2bf(bv[2]), f2bf(bv[3]) };
            *(u16x4*)&As[row][c4] = aw;
            *(u16x4*)&Bs[row][c4] = bw;
        }
        __syncthreads();
#pragma unroll
        for (int ks = 0; ks < 2; ++ks) {
            int ko = (ks << 5) + ((lane >> 4) << 3);
            bf16x8 af[4], bfv[4];
#pragma unroll
            for (int m = 0; m < 4; ++m) af[m]  = ldfrag(&As[(wm << 6) + (m << 4) + (lane & 15)][ko]);
#pragma unroll
            for (int n = 0; n < 4; ++n) bfv[n] = ldfrag(&Bs[(wn << 6) + (n << 4) + (lane & 15)][ko]);
#pragma unroll
            for (int m = 0; m < 4; ++m)
#pragma unroll
                for (int n = 0; n < 4; ++n)
                    acc[m][n] = __builtin_amdgcn_mfma_f32_16x16x32_bf16(af[m], bfv[n], acc[m][n], 0, 0, 0);
        }
        __syncthreads();
    }

    // epilogue: scatter into batch[l,s,b,h,T,d] with bias
    int cum = ws[16 + bs];
    int b = bs >> 2;
    int lidx = g >> 3;
    int s = (g >> 2) & 1;
    int dhi = (g & 3) << 4;
    float* batch = out + 12288;
    const float* biasg = bias + (g << 8);

#pragma unroll
    for (int m = 0; m < 4; ++m) {
        int obase = (mt << 7) + (wm << 6) + (m << 4) + ((lane >> 4) << 2);
#pragma unroll
        for (int r = 0; r < 4; ++r) {
            int oo = obase + r;            // o within [0,256)
            int h = oo & 15;
            int d = dhi + (oo >> 4);
            float bv = biasg[oo];
            size_t rowbase = ((size_t)(((lidx * 2 + s) * 4 + b) * 16 + h)) * Tmax;
#pragma unroll
            for (int n = 0; n < 4; ++n) {
                int t = tbase + (wn << 6) + (n << 4) + (lane & 15);
                if (t < len) {
                    batch[(rowbase + cum + t) * 64 + d] = acc[m][n][r] + bv;
                }
            }
        }
    }
}

extern "C" void kernel_launch(void* const* d_in, const int* in_sizes, int n_in,
                              void* d_out, int out_size, void* d_ws, size_t ws_size,
                              hipStream_t stream) {
    const float* lh   = (const float*)d_in[0];
    const int*   mask = (const int*)d_in[1];
    const float* wgt  = (const float*)d_in[2];
    const float* bias = (const float*)d_in[3];
    float* out = (float*)d_out;
    int* ws = (int*)d_ws;

    int Tmax = (out_size - 12288) / 131076;

    prep_kernel<<<16, 256, 0, stream>>>(lh, mask, out, ws);
    cums_kernel<<<1, 256, 0, stream>>>(ws, out + 12288 + (size_t)131072 * Tmax, Tmax);

    int tailN = Tmax - 512; if (tailN < 1) tailN = 1;
    int nz = 4 * tailN * 8192;
    zerotail_kernel<<<(nz + 255) / 256, 256, 0, stream>>>(out + 12288, ws, Tmax, tailN);

    gemm_kernel<<<16 * 128 * 4, 256, 0, stream>>>(lh, wgt, bias, ws, out, Tmax);
}

// Round 2
// 358.663 us; speedup vs baseline: 2.7021x; 2.7021x over previous
//
#include <hip/hip_runtime.h>
#include <hip/hip_bf16.h>

// dims: Bk=16, n=256, E=768, G=128, Cout_g=256, Cin_g=192, B=4, K=4, L=16, H=16, D=64
// out = [pooled 16*768][batch 131072*Tmax][valid 4*Tmax]
// ws (int32): [0..15] len per bseq, [16..31] cum, [32..35] total per b

typedef float f32x4 __attribute__((ext_vector_type(4)));
typedef __bf16 bf16x8 __attribute__((ext_vector_type(8)));
typedef unsigned short u16x4 __attribute__((ext_vector_type(4)));
typedef unsigned short u16x8 __attribute__((ext_vector_type(8)));

__device__ __forceinline__ unsigned short f2bf(float f) {
    union { float f; unsigned u; } v; v.f = f;
    unsigned r = v.u + 0x7FFFu + ((v.u >> 16) & 1u);
    return (unsigned short)(r >> 16);
}

__device__ __forceinline__ bf16x8 ldfrag(const unsigned short* p) {
    u16x8 r = *(const u16x8*)p;
    return __builtin_bit_cast(bf16x8, r);
}

// lens + prefix sums + valid flags, one block of 1024 threads
__global__ void cums_kernel(const int* __restrict__ mask, int* __restrict__ ws,
                            float* __restrict__ valid_out, int Tmax) {
    int tid = threadIdx.x;
    int w = tid >> 6, lane = tid & 63;
    int m = mask[w * 256 + lane] + mask[w * 256 + lane + 64] +
            mask[w * 256 + lane + 128] + mask[w * 256 + lane + 192];
#pragma unroll
    for (int off = 32; off > 0; off >>= 1) m += __shfl_down(m, off);
    if (lane == 0) ws[w] = m;
    __syncthreads();
    if (tid == 0) {
        for (int b = 0; b < 4; ++b) {
            int c = 0;
            for (int j = 0; j < 4; ++j) { ws[16 + b * 4 + j] = c; c += ws[b * 4 + j]; }
            ws[32 + b] = c;
        }
    }
    __syncthreads();
    for (int i = tid; i < 4 * Tmax; i += 1024) {
        int b = i / Tmax;
        int T = i - b * Tmax;
        valid_out[i] = (T < ws[32 + b]) ? 1.0f : 0.0f;
    }
}

// pooled: block = (bs, e-chunk of 64), 256 threads = 4 t-groups x 64 e
__global__ void pooled_kernel(const float* __restrict__ lh, const int* __restrict__ mask,
                              const int* __restrict__ ws, float* __restrict__ pooled) {
    int bs = blockIdx.x / 12;
    int ec = blockIdx.x - bs * 12;
    int tid = threadIdx.x;
    int tg = tid >> 6, lane = tid & 63;
    int e = ec * 64 + lane;
    float s = 0.f;
    for (int t = tg; t < 256; t += 4) {
        float mf = (float)mask[bs * 256 + t];
        s += lh[(size_t)(bs * 256 + t) * 768 + e] * mf;
    }
    __shared__ float red[4][64];
    red[tg][lane] = s;
    __syncthreads();
    if (tg == 0) {
        float tot = red[0][lane] + red[1][lane] + red[2][lane] + red[3][lane];
        pooled[bs * 768 + e] = tot / (float)ws[bs];
    }
}

// zero batch[l,s,b,h,T,d] for T in [total[b], Tmax)
__global__ void zerotail_kernel(float* __restrict__ batch, const int* __restrict__ ws,
                                int Tmax, int tailN) {
    int i = blockIdx.x * 256 + threadIdx.x;
    int per = tailN * 8192;
    if (i >= 4 * per) return;
    int b = i / per;
    int r = i - b * per;
    int toff = r >> 13;
    int q = r & 8191;
    int T = Tmax - 1 - toff;
    if (T < ws[32 + b]) return;
    int l = q >> 9, s = (q >> 8) & 1, h = (q >> 4) & 15, dq = q & 15;
    size_t off = ((((size_t)((l * 2 + s) * 4 + b) * 16 + h) * Tmax + T) * 64) + (dq << 2);
    f32x4 z = {0.f, 0.f, 0.f, 0.f};
    *(f32x4*)(batch + off) = z;
}

// block = (g, bs, nthalf): M=256 (o), N=128 (t), K=192. 512 threads = 8 waves (2 wm x 4 wn),
// wave tile 128x32, fragments acc[8][2].
__global__ __launch_bounds__(512) void gemm_kernel(
    const float* __restrict__ lh, const float* __restrict__ wgt,
    const float* __restrict__ bias, const int* __restrict__ ws,
    float* __restrict__ out, int Tmax) {
    __shared__ __align__(16) unsigned short As[256][72];   // [o][k], pad 8
    __shared__ __align__(16) unsigned short Bs[128][72];   // [t][k], pad 8

    int x = blockIdx.x;
    int bsnt = x & 31;
    int g = x >> 5;
    int bs = bsnt >> 1;
    int nthalf = bsnt & 1;

    int len = ws[bs];
    int tbase = nthalf * 128;
    if (tbase >= len) return;

    int beta = g & 3;
    const float* Ag = wgt + (size_t)g * 49152;
    const float* Bg = lh + (size_t)bs * 196608 + (size_t)tbase * 768 + beta * 192;

    int tid = threadIdx.x;
    int lane = tid & 63;
    int wave = tid >> 6;
    int wm = wave >> 2, wn = wave & 3;

    f32x4 acc[8][2] = {};

    for (int kk = 0; kk < 192; kk += 64) {
#pragma unroll
        for (int it = 0; it < 8; ++it) {
            int idx = tid + (it << 9);           // 0..4095
            int row = idx >> 4;
            int c4 = (idx & 15) << 2;
            f32x4 av = *(const f32x4*)(Ag + row * 192 + kk + c4);
            u16x4 aw = { f2bf(av[0]), f2bf(av[1]), f2bf(av[2]), f2bf(av[3]) };
            *(u16x4*)&As[row][c4] = aw;
        }
#pragma unroll
        for (int it = 0; it < 4; ++it) {
            int idx = tid + (it << 9);           // 0..2047
            int row = idx >> 4;
            int c4 = (idx & 15) << 2;
            f32x4 bv = *(const f32x4*)(Bg + row * 768 + kk + c4);
            u16x4 bw = { f2bf(bv[0]), f2bf(bv[1]), f2bf(bv[2]), f2bf(bv[3]) };
            *(u16x4*)&Bs[row][c4] = bw;
        }
        __syncthreads();
#pragma unroll
        for (int ks = 0; ks < 2; ++ks) {
            int ko = (ks << 5) + ((lane >> 4) << 3);
            bf16x8 bfv[2];
#pragma unroll
            for (int n = 0; n < 2; ++n)
                bfv[n] = ldfrag(&Bs[(wn << 5) + (n << 4) + (lane & 15)][ko]);
#pragma unroll
            for (int mh = 0; mh < 2; ++mh) {
                bf16x8 af[4];
#pragma unroll
                for (int mi = 0; mi < 4; ++mi)
                    af[mi] = ldfrag(&As[(wm << 7) + (mh << 6) + (mi << 4) + (lane & 15)][ko]);
#pragma unroll
                for (int mi = 0; mi < 4; ++mi)
#pragma unroll
                    for (int n = 0; n < 2; ++n)
                        acc[(mh << 2) + mi][n] =
                            __builtin_amdgcn_mfma_f32_16x16x32_bf16(af[mi], bfv[n], acc[(mh << 2) + mi][n], 0, 0, 0);
            }
        }
        __syncthreads();
    }

    // epilogue: d = dhi + wm*8 + m (m=0..7 contiguous), h = (lane>>4)*4 + r, t = tbase + wn*32 + n*16 + (lane&15)
    int cum = ws[16 + bs];
    int b = bs >> 2;
    int lidx = g >> 3;
    int s = (g >> 2) & 1;
    int dhi = (g & 3) << 4;
    float* batch = out + 12288;

    f32x4 bias4[8];
#pragma unroll
    for (int m = 0; m < 8; ++m)
        bias4[m] = *(const f32x4*)(bias + (g << 8) + (wm << 7) + (m << 4) + ((lane >> 4) << 2));

    int d0 = dhi + (wm << 3);
    size_t hdbase = (size_t)((lidx * 2 + s) * 4 + b) * 16;

#pragma unroll
    for (int n = 0; n < 2; ++n) {
        int t = tbase + (wn << 5) + (n << 4) + (lane & 15);
        if (t >= len) continue;
        size_t tb = (size_t)(cum + t);
#pragma unroll
        for (int r = 0; r < 4; ++r) {
            int h = ((lane >> 4) << 2) + r;
            size_t off = (((hdbase + h) * Tmax + tb) << 6) + d0;
            f32x4 lo = { acc[0][n][r] + bias4[0][r], acc[1][n][r] + bias4[1][r],
                         acc[2][n][r] + bias4[2][r], acc[3][n][r] + bias4[3][r] };
            f32x4 hi = { acc[4][n][r] + bias4[4][r], acc[5][n][r] + bias4[5][r],
                         acc[6][n][r] + bias4[6][r], acc[7][n][r] + bias4[7][r] };
            *(f32x4*)(batch + off) = lo;
            *(f32x4*)(batch + off + 4) = hi;
        }
    }
}

extern "C" void kernel_launch(void* const* d_in, const int* in_sizes, int n_in,
                              void* d_out, int out_size, void* d_ws, size_t ws_size,
                              hipStream_t stream) {
    const float* lh   = (const float*)d_in[0];
    const int*   mask = (const int*)d_in[1];
    const float* wgt  = (const float*)d_in[2];
    const float* bias = (const float*)d_in[3];
    float* out = (float*)d_out;
    int* ws = (int*)d_ws;

    int Tmax = (out_size - 12288) / 131076;

    cums_kernel<<<1, 1024, 0, stream>>>(mask, ws, out + 12288 + (size_t)131072 * Tmax, Tmax);
    pooled_kernel<<<16 * 12, 256, 0, stream>>>(lh, mask, ws, out);

    int tailN = Tmax - 512; if (tailN < 1) tailN = 1;
    int nz = 4 * tailN * 8192;
    zerotail_kernel<<<(nz + 255) / 256, 256, 0, stream>>>(out + 12288, ws, Tmax, tailN);

    gemm_kernel<<<128 * 32, 512, 0, stream>>>(lh, wgt, bias, ws, out, Tmax);
}